// Round 6
// baseline (380.322 us; speedup 1.0000x reference)
//
#include <hip/hip_runtime.h>

#define BN_EPS 1e-5f

typedef __attribute__((ext_vector_type(8))) short bf16x8;
typedef __attribute__((ext_vector_type(4))) float f32x4;

__device__ __forceinline__ short f2bf(float f) {
    union { float f; unsigned u; } v; v.f = f;
    unsigned r = (v.u + 0x7fffu + ((v.u >> 16) & 1u)) >> 16;
    return (short)r;
}
__device__ __forceinline__ float bflo(unsigned d) {
    union { unsigned u; float f; } v; v.u = d << 16; return v.f;
}
__device__ __forceinline__ float bfhi(unsigned d) {
    union { unsigned u; float f; } v; v.u = d & 0xffff0000u; return v.f;
}

// ---------------------------------------------------------------------------
// Build CSR offsets from sorted dst. off[n] = first edge index with dst >= n.
// ---------------------------------------------------------------------------
__global__ __launch_bounds__(256) void build_off_k(const int* __restrict__ dst,
                                                   int* __restrict__ off, int E, int N) {
    int i = blockIdx.x * 256 + threadIdx.x;
    if (i > E) return;
    int cur  = (i < E) ? dst[i] : N;
    int prev = (i == 0) ? -1 : dst[i - 1];
    for (int n = prev + 1; n <= cur; ++n) off[n] = i;
}

__global__ void zero_k(float* p, int n) {
    int i = blockIdx.x * blockDim.x + threadIdx.x;
    if (i < n) p[i] = 0.f;
}

// Transpose + convert weights: Wt[c][k] = bf16(W[k][c]).
__global__ __launch_bounds__(256) void wtrans_k(const float* __restrict__ W,
                                                short* __restrict__ Wt, int K, int C) {
    int i = blockIdx.x * 256 + threadIdx.x;
    if (i >= K * C) return;
    int c = i / K, k = i % K;
    Wt[i] = f2bf(W[k * C + c]);
}

// ---------------------------------------------------------------------------
// MFMA GEMM, 3 modes of A-input fusion:
//   MODE 0: A = bf16(X fp32)                                   (layer 0)
//   MODE 1: A = relu(Hb*sc+sh + R_fp32); also write A -> X1    (layer 1)
//   MODE 2: A = relu(Hb*sc+sh + R_bf16)                        (layer 2)
// Hb is bf16 [N][128]. Output M row-major bf16 [N][OUTC].
// Block = 256 thr (4 waves), 128 rows. mfma_f32_16x16x32_bf16 (m89-verified).
// ---------------------------------------------------------------------------
template <int OUTC, int MODE>
__global__ __launch_bounds__(256) void mgemm_k(const void* __restrict__ Xp,
                                               const short* __restrict__ Wt,
                                               short* __restrict__ M,
                                               const float* __restrict__ ss,
                                               const void* __restrict__ Rp,
                                               short* __restrict__ X1, int N) {
    constexpr int NR = OUTC / 16;
    __shared__ short sW[OUTC][136];          // 272B stride: 2-way conflict = free

    const int tid = threadIdx.x;
    for (int q = tid; q < OUTC * 16; q += 256) {
        int r = q >> 4, s = q & 15;
        *(int4*)&sW[r][s * 8] = ((const int4*)Wt)[q];
    }
    __syncthreads();

    const int wave = tid >> 6, lane = tid & 63;
    const int lr = lane & 15, lg = lane >> 4;
    const int row0 = blockIdx.x * 128 + wave * 32;

    f32x4 acc[2][NR];
    #pragma unroll
    for (int m = 0; m < 2; ++m)
        #pragma unroll
        for (int n = 0; n < NR; ++n) acc[m][n] = (f32x4){0.f, 0.f, 0.f, 0.f};

    #pragma unroll
    for (int kk = 0; kk < 4; ++kk) {
        bf16x8 a[2];
        const int ch0 = kk * 32 + lg * 8;
        #pragma unroll
        for (int m = 0; m < 2; ++m) {
            int row = row0 + m * 16 + lr;
            float v[8] = {0.f, 0.f, 0.f, 0.f, 0.f, 0.f, 0.f, 0.f};
            if (row < N) {
                if constexpr (MODE == 0) {
                    const float4* p = (const float4*)((const float*)Xp + (size_t)row * 128 + ch0);
                    float4 h0 = p[0], h1 = p[1];
                    v[0] = h0.x; v[1] = h0.y; v[2] = h0.z; v[3] = h0.w;
                    v[4] = h1.x; v[5] = h1.y; v[6] = h1.z; v[7] = h1.w;
                } else {
                    int4 hb = *(const int4*)((const short*)Xp + (size_t)row * 128 + ch0);
                    v[0] = bflo(hb.x); v[1] = bfhi(hb.x);
                    v[2] = bflo(hb.y); v[3] = bfhi(hb.y);
                    v[4] = bflo(hb.z); v[5] = bfhi(hb.z);
                    v[6] = bflo(hb.w); v[7] = bfhi(hb.w);
                    float4 sc0 = *(const float4*)&ss[ch0];
                    float4 sc1 = *(const float4*)&ss[ch0 + 4];
                    float4 sh0 = *(const float4*)&ss[128 + ch0];
                    float4 sh1 = *(const float4*)&ss[128 + ch0 + 4];
                    float sc[8] = {sc0.x, sc0.y, sc0.z, sc0.w, sc1.x, sc1.y, sc1.z, sc1.w};
                    float sh[8] = {sh0.x, sh0.y, sh0.z, sh0.w, sh1.x, sh1.y, sh1.z, sh1.w};
                    float r[8];
                    if constexpr (MODE == 1) {
                        const float4* rp = (const float4*)((const float*)Rp + (size_t)row * 128 + ch0);
                        float4 r0 = rp[0], r1 = rp[1];
                        r[0] = r0.x; r[1] = r0.y; r[2] = r0.z; r[3] = r0.w;
                        r[4] = r1.x; r[5] = r1.y; r[6] = r1.z; r[7] = r1.w;
                    } else {
                        int4 rb = *(const int4*)((const short*)Rp + (size_t)row * 128 + ch0);
                        r[0] = bflo(rb.x); r[1] = bfhi(rb.x);
                        r[2] = bflo(rb.y); r[3] = bfhi(rb.y);
                        r[4] = bflo(rb.z); r[5] = bfhi(rb.z);
                        r[6] = bflo(rb.w); r[7] = bfhi(rb.w);
                    }
                    #pragma unroll
                    for (int k = 0; k < 8; ++k)
                        v[k] = fmaxf(fmaf(v[k], sc[k], sh[k]) + r[k], 0.f);
                }
            }
            #pragma unroll
            for (int k = 0; k < 8; ++k) a[m][k] = f2bf(v[k]);
            if constexpr (MODE == 1) {
                if (row < N) *(bf16x8*)&X1[(size_t)row * 128 + ch0] = a[m];
            }
        }
        #pragma unroll
        for (int n = 0; n < NR; ++n) {
            bf16x8 b = *(const bf16x8*)&sW[n * 16 + lr][kk * 32 + lg * 8];
            acc[0][n] = __builtin_amdgcn_mfma_f32_16x16x32_bf16(a[0], b, acc[0][n], 0, 0, 0);
            acc[1][n] = __builtin_amdgcn_mfma_f32_16x16x32_bf16(a[1], b, acc[1][n], 0, 0, 0);
        }
    }

    #pragma unroll
    for (int m = 0; m < 2; ++m)
        #pragma unroll
        for (int r = 0; r < 4; ++r) {
            int row = row0 + m * 16 + lg * 4 + r;
            if (row < N) {
                #pragma unroll
                for (int n = 0; n < NR; ++n)
                    M[(size_t)row * OUTC + n * 16 + lr] = f2bf(acc[m][n][r]);
            }
        }
}

// ---------------------------------------------------------------------------
// Segment-sum aggregation over row-major bf16 M (dst sorted -> CSR).
// Wave layout: lane = g*T + t. G edge-slots x T 16B-chunks; 4 independent
// dwordx4 wave-loads in flight (4KB/wave). Butterfly-reduce edge-slot dim.
// OUTBF: write H as bf16 (layers 0/1); else fp32 (final output).
// STATS: accumulate BN column stats (sum,sumsq) -> LDS -> atomics.
// ---------------------------------------------------------------------------
template <int C, bool STATS, bool OUTBF>
__global__ __launch_bounds__(256) void agg_k(const short* __restrict__ M,
                                             const int* __restrict__ src,
                                             const int* __restrict__ off,
                                             const float* __restrict__ bias,
                                             void* __restrict__ Hp,
                                             float* __restrict__ stats, int N) {
    constexpr int T = C / 8;                 // 16B chunks per row (16 or 8)
    constexpr int G = 64 / T;                // edge slots (4 or 8)
    const int wave = threadIdx.x >> 6, lane = threadIdx.x & 63;
    const int g = lane / T, t = lane % T;
    const uint4* __restrict__ Mq = (const uint4*)M;

    float sum[8], sq[8];
    if constexpr (STATS) {
        #pragma unroll
        for (int k = 0; k < 8; ++k) { sum[k] = 0.f; sq[k] = 0.f; }
    }

    for (int node = blockIdx.x * 4 + wave; node < N; node += gridDim.x * 4) {
        const int e0 = off[node], e1 = off[node + 1];
        float acc[8];
        #pragma unroll
        for (int k = 0; k < 8; ++k) acc[k] = 0.f;

        for (int base = e0; base < e1; base += 64) {
            int cnt = e1 - base; if (cnt > 64) cnt = 64;
            int s = (base + lane < e1) ? src[base + lane] : 0;
            int ngrp = (cnt + G - 1) / G;
            for (int j = 0; j < ngrp; j += 4) {
                int i0 = j * G + g, i1 = i0 + G, i2 = i0 + 2 * G, i3 = i0 + 3 * G;
                int s0 = __shfl(s, i0 & 63), s1 = __shfl(s, i1 & 63);
                int s2 = __shfl(s, i2 & 63), s3 = __shfl(s, i3 & 63);
                uint4 d0 = make_uint4(0u,0u,0u,0u), d1 = d0, d2 = d0, d3 = d0;
                if (i0 < cnt) d0 = Mq[(size_t)s0 * T + t];
                if (i1 < cnt) d1 = Mq[(size_t)s1 * T + t];
                if (i2 < cnt) d2 = Mq[(size_t)s2 * T + t];
                if (i3 < cnt) d3 = Mq[(size_t)s3 * T + t];
                acc[0] += bflo(d0.x) + bflo(d1.x); acc[1] += bfhi(d0.x) + bfhi(d1.x);
                acc[2] += bflo(d0.y) + bflo(d1.y); acc[3] += bfhi(d0.y) + bfhi(d1.y);
                acc[4] += bflo(d0.z) + bflo(d1.z); acc[5] += bfhi(d0.z) + bfhi(d1.z);
                acc[6] += bflo(d0.w) + bflo(d1.w); acc[7] += bfhi(d0.w) + bfhi(d1.w);
                acc[0] += bflo(d2.x) + bflo(d3.x); acc[1] += bfhi(d2.x) + bfhi(d3.x);
                acc[2] += bflo(d2.y) + bflo(d3.y); acc[3] += bfhi(d2.y) + bfhi(d3.y);
                acc[4] += bflo(d2.z) + bflo(d3.z); acc[5] += bfhi(d2.z) + bfhi(d3.z);
                acc[6] += bflo(d2.w) + bflo(d3.w); acc[7] += bfhi(d2.w) + bfhi(d3.w);
            }
        }
        // reduce over edge-slot dimension (upper lane bits)
        #pragma unroll
        for (int dlt = T; dlt < 64; dlt <<= 1)
            #pragma unroll
            for (int k = 0; k < 8; ++k) acc[k] += __shfl_xor(acc[k], dlt);

        if (g == 0) {
            float h[8];
            #pragma unroll
            for (int k = 0; k < 8; ++k) h[k] = acc[k] + bias[t * 8 + k];
            if constexpr (OUTBF) {
                bf16x8 hv;
                #pragma unroll
                for (int k = 0; k < 8; ++k) hv[k] = f2bf(h[k]);
                *(bf16x8*)((short*)Hp + (size_t)node * C + t * 8) = hv;
            } else {
                *(float4*)((float*)Hp + (size_t)node * C + t * 8)     = make_float4(h[0], h[1], h[2], h[3]);
                *(float4*)((float*)Hp + (size_t)node * C + t * 8 + 4) = make_float4(h[4], h[5], h[6], h[7]);
            }
            if constexpr (STATS) {
                #pragma unroll
                for (int k = 0; k < 8; ++k) {
                    sum[k] += h[k]; sq[k] = fmaf(h[k], h[k], sq[k]);
                }
            }
        }
    }

    if constexpr (STATS) {
        __shared__ float sL[4 * 256];
        if (g == 0) {
            #pragma unroll
            for (int k = 0; k < 8; ++k) {
                sL[wave * 256 + t * 8 + k]       = sum[k];
                sL[wave * 256 + 128 + t * 8 + k] = sq[k];
            }
        }
        __syncthreads();
        int tid = threadIdx.x;
        float v = sL[tid] + sL[256 + tid] + sL[512 + tid] + sL[768 + tid];
        atomicAdd(&stats[tid], v);
    }
}

// stats -> per-channel scale/shift:  out = h*sc + sh
__global__ void bnfin_k(const float* __restrict__ stats, const float* __restrict__ gamma,
                        const float* __restrict__ beta, float* __restrict__ ss, float invN) {
    int c = threadIdx.x;   // 128 threads
    float mu  = stats[c] * invN;
    float var = fmaf(-mu, mu, stats[128 + c] * invN);
    float sc  = gamma[c] * rsqrtf(var + BN_EPS);
    ss[c]       = sc;
    ss[128 + c] = fmaf(-mu, sc, beta[c]);
}

// ---------------------------------------------------------------------------
extern "C" void kernel_launch(void* const* d_in, const int* in_sizes, int n_in,
                              void* d_out, int out_size, void* d_ws, size_t ws_size,
                              hipStream_t stream) {
    const float* x   = (const float*)d_in[0];
    const int*   src = (const int*)d_in[1];
    const int*   dst = (const int*)d_in[2];
    const float* W0  = (const float*)d_in[3];
    const float* b0  = (const float*)d_in[4];
    const float* W1  = (const float*)d_in[5];
    const float* b1  = (const float*)d_in[6];
    const float* W2  = (const float*)d_in[7];
    const float* b2  = (const float*)d_in[8];
    const float* g0  = (const float*)d_in[9];
    const float* be0 = (const float*)d_in[10];
    const float* g1  = (const float*)d_in[11];
    const float* be1 = (const float*)d_in[12];
    float* out = (float*)d_out;

    const int N = in_sizes[0] / 128;
    const int E = in_sizes[1];

    // workspace: bf16 M (N x 128) + bf16 Hb (N x 128) + bf16 X1 (N x 128) + misc
    char*  ws   = (char*)d_ws;
    size_t bufH = (size_t)N * 128 * sizeof(short);
    short* Mb = (short*)(ws);                 // conv GEMM output, bf16
    short* Hb = (short*)(ws + bufH);          // pre-BN agg output, bf16
    short* X1 = (short*)(ws + 2 * bufH);      // post-layer-1 activations, bf16
    size_t p  = 3 * bufH;
    p = (p + 255) & ~(size_t)255;
    int*   off = (int*)(ws + p);
    p += ((size_t)(N + 1) * sizeof(int) + 255) & ~(size_t)255;
    float* stats0 = (float*)(ws + p); p += 1024;
    float* stats1 = (float*)(ws + p); p += 1024;
    float* ss0    = (float*)(ws + p); p += 1024;
    float* ss1    = (float*)(ws + p); p += 1024;
    short* Wt0    = (short*)(ws + p); p += 128 * 128 * 2;
    short* Wt1    = (short*)(ws + p); p += 128 * 128 * 2;
    short* Wt2    = (short*)(ws + p); p += 128 * 64 * 2;

    const dim3 blk(256);
    const int gGemm = (N + 127) / 128;
    const int gAgg  = 4096;                   // 16384 waves: 2x oversubscribed
    const float invN = 1.f / (float)N;

    zero_k<<<2, blk, 0, stream>>>(stats0, 512);   // stats0+stats1 contiguous
    wtrans_k<<<64, blk, 0, stream>>>(W0, Wt0, 128, 128);
    wtrans_k<<<64, blk, 0, stream>>>(W1, Wt1, 128, 128);
    wtrans_k<<<32, blk, 0, stream>>>(W2, Wt2, 128, 64);
    build_off_k<<<(E + 256) / 256, blk, 0, stream>>>(dst, off, E, N);

    // ---- layer 0: M0 = bf16(x) @ W0 ; Hb = agg(M0)+b0 (+stats) ----
    mgemm_k<128, 0><<<gGemm, blk, 0, stream>>>(x, Wt0, Mb, nullptr, nullptr, nullptr, N);
    agg_k<128, true, true><<<gAgg, blk, 0, stream>>>(Mb, src, off, b0, Hb, stats0, N);
    bnfin_k<<<1, 128, 0, stream>>>(stats0, g0, be0, ss0, invN);

    // ---- layer 1: x1 = relu(BN(Hb)+x) fused into GEMM; M1 = x1 @ W1 ----
    mgemm_k<128, 1><<<gGemm, blk, 0, stream>>>(Hb, Wt1, Mb, ss0, x, X1, N);
    agg_k<128, true, true><<<gAgg, blk, 0, stream>>>(Mb, src, off, b1, Hb, stats1, N);
    bnfin_k<<<1, 128, 0, stream>>>(stats1, g1, be1, ss1, invN);

    // ---- layer 2: x2 = relu(BN(Hb)+x1) fused; M2 = x2 @ W2 ; out = agg+b2 ----
    mgemm_k<64, 2><<<gGemm, blk, 0, stream>>>(Hb, Wt2, Mb, ss1, X1, nullptr, N);
    agg_k<64, false, false><<<gAgg, blk, 0, stream>>>(Mb, src, off, b2, out, stats0, N);
}

// Round 7
// 370.136 us; speedup vs baseline: 1.0275x; 1.0275x over previous
//
#include <hip/hip_runtime.h>

#define BN_EPS 1e-5f

typedef __attribute__((ext_vector_type(8))) short bf16x8;
typedef __attribute__((ext_vector_type(4))) float f32x4;

__device__ __forceinline__ short f2bf(float f) {
    union { float f; unsigned u; } v; v.f = f;
    unsigned r = (v.u + 0x7fffu + ((v.u >> 16) & 1u)) >> 16;
    return (short)r;
}
__device__ __forceinline__ float bflo(unsigned d) {
    union { unsigned u; float f; } v; v.u = d << 16; return v.f;
}
__device__ __forceinline__ float bfhi(unsigned d) {
    union { unsigned u; float f; } v; v.u = d & 0xffff0000u; return v.f;
}

// ---------------------------------------------------------------------------
// Build CSR offsets from sorted dst. off[n] = first edge index with dst >= n.
// ---------------------------------------------------------------------------
__global__ __launch_bounds__(256) void build_off_k(const int* __restrict__ dst,
                                                   int* __restrict__ off, int E, int N) {
    int i = blockIdx.x * 256 + threadIdx.x;
    if (i > E) return;
    int cur  = (i < E) ? dst[i] : N;
    int prev = (i == 0) ? -1 : dst[i - 1];
    for (int n = prev + 1; n <= cur; ++n) off[n] = i;
}

__global__ void zero_k(float* p, int n) {
    int i = blockIdx.x * blockDim.x + threadIdx.x;
    if (i < n) p[i] = 0.f;
}

// Transpose + convert weights: Wt[c][k] = bf16(W[k][c]).
__global__ __launch_bounds__(256) void wtrans_k(const float* __restrict__ W,
                                                short* __restrict__ Wt, int K, int C) {
    int i = blockIdx.x * 256 + threadIdx.x;
    if (i >= K * C) return;
    int c = i / K, k = i % K;
    Wt[i] = f2bf(W[k * C + c]);
}

// ---------------------------------------------------------------------------
// MFMA GEMM, 3 modes of A-input fusion:
//   MODE 0: A = bf16(X fp32)                                   (layer 0)
//   MODE 1: A = relu(Hb*sc+sh + R_fp32); also write A -> X1    (layer 1)
//   MODE 2: A = relu(Hb*sc+sh + R_bf16)                        (layer 2)
// Hb is bf16 [N][128]. Output M row-major bf16 [N][OUTC].
// Block = 256 thr (4 waves), 128 rows. mfma_f32_16x16x32_bf16 (m89-verified).
// ---------------------------------------------------------------------------
template <int OUTC, int MODE>
__global__ __launch_bounds__(256) void mgemm_k(const void* __restrict__ Xp,
                                               const short* __restrict__ Wt,
                                               short* __restrict__ M,
                                               const float* __restrict__ ss,
                                               const void* __restrict__ Rp,
                                               short* __restrict__ X1, int N) {
    constexpr int NR = OUTC / 16;
    __shared__ short sW[OUTC][136];          // 272B stride: 2-way conflict = free

    const int tid = threadIdx.x;
    for (int q = tid; q < OUTC * 16; q += 256) {
        int r = q >> 4, s = q & 15;
        *(int4*)&sW[r][s * 8] = ((const int4*)Wt)[q];
    }
    __syncthreads();

    const int wave = tid >> 6, lane = tid & 63;
    const int lr = lane & 15, lg = lane >> 4;
    const int row0 = blockIdx.x * 128 + wave * 32;

    f32x4 acc[2][NR];
    #pragma unroll
    for (int m = 0; m < 2; ++m)
        #pragma unroll
        for (int n = 0; n < NR; ++n) acc[m][n] = (f32x4){0.f, 0.f, 0.f, 0.f};

    #pragma unroll
    for (int kk = 0; kk < 4; ++kk) {
        bf16x8 a[2];
        const int ch0 = kk * 32 + lg * 8;
        #pragma unroll
        for (int m = 0; m < 2; ++m) {
            int row = row0 + m * 16 + lr;
            float v[8] = {0.f, 0.f, 0.f, 0.f, 0.f, 0.f, 0.f, 0.f};
            if (row < N) {
                if constexpr (MODE == 0) {
                    const float4* p = (const float4*)((const float*)Xp + (size_t)row * 128 + ch0);
                    float4 h0 = p[0], h1 = p[1];
                    v[0] = h0.x; v[1] = h0.y; v[2] = h0.z; v[3] = h0.w;
                    v[4] = h1.x; v[5] = h1.y; v[6] = h1.z; v[7] = h1.w;
                } else {
                    int4 hb = *(const int4*)((const short*)Xp + (size_t)row * 128 + ch0);
                    v[0] = bflo(hb.x); v[1] = bfhi(hb.x);
                    v[2] = bflo(hb.y); v[3] = bfhi(hb.y);
                    v[4] = bflo(hb.z); v[5] = bfhi(hb.z);
                    v[6] = bflo(hb.w); v[7] = bfhi(hb.w);
                    float4 sc0 = *(const float4*)&ss[ch0];
                    float4 sc1 = *(const float4*)&ss[ch0 + 4];
                    float4 sh0 = *(const float4*)&ss[128 + ch0];
                    float4 sh1 = *(const float4*)&ss[128 + ch0 + 4];
                    float sc[8] = {sc0.x, sc0.y, sc0.z, sc0.w, sc1.x, sc1.y, sc1.z, sc1.w};
                    float sh[8] = {sh0.x, sh0.y, sh0.z, sh0.w, sh1.x, sh1.y, sh1.z, sh1.w};
                    float r[8];
                    if constexpr (MODE == 1) {
                        const float4* rp = (const float4*)((const float*)Rp + (size_t)row * 128 + ch0);
                        float4 r0 = rp[0], r1 = rp[1];
                        r[0] = r0.x; r[1] = r0.y; r[2] = r0.z; r[3] = r0.w;
                        r[4] = r1.x; r[5] = r1.y; r[6] = r1.z; r[7] = r1.w;
                    } else {
                        int4 rb = *(const int4*)((const short*)Rp + (size_t)row * 128 + ch0);
                        r[0] = bflo(rb.x); r[1] = bfhi(rb.x);
                        r[2] = bflo(rb.y); r[3] = bfhi(rb.y);
                        r[4] = bflo(rb.z); r[5] = bfhi(rb.z);
                        r[6] = bflo(rb.w); r[7] = bfhi(rb.w);
                    }
                    #pragma unroll
                    for (int k = 0; k < 8; ++k)
                        v[k] = fmaxf(fmaf(v[k], sc[k], sh[k]) + r[k], 0.f);
                }
            }
            #pragma unroll
            for (int k = 0; k < 8; ++k) a[m][k] = f2bf(v[k]);
            if constexpr (MODE == 1) {
                if (row < N) *(bf16x8*)&X1[(size_t)row * 128 + ch0] = a[m];
            }
        }
        #pragma unroll
        for (int n = 0; n < NR; ++n) {
            bf16x8 b = *(const bf16x8*)&sW[n * 16 + lr][kk * 32 + lg * 8];
            acc[0][n] = __builtin_amdgcn_mfma_f32_16x16x32_bf16(a[0], b, acc[0][n], 0, 0, 0);
            acc[1][n] = __builtin_amdgcn_mfma_f32_16x16x32_bf16(a[1], b, acc[1][n], 0, 0, 0);
        }
    }

    #pragma unroll
    for (int m = 0; m < 2; ++m)
        #pragma unroll
        for (int r = 0; r < 4; ++r) {
            int row = row0 + m * 16 + lg * 4 + r;
            if (row < N) {
                #pragma unroll
                for (int n = 0; n < NR; ++n)
                    M[(size_t)row * OUTC + n * 16 + lr] = f2bf(acc[m][n][r]);
            }
        }
}

// ---------------------------------------------------------------------------
// Segment-sum aggregation over row-major bf16 M (dst sorted -> CSR).
// Round-3 proven structure: ONE NODE PER WAVE, lane covers a dword (2 ch),
// one wave-load = one contiguous 256B row, 4 independent edges in flight.
// OUTBF: write H as bf16 (layers 0/1); else fp32 (final 64-ch output).
// ---------------------------------------------------------------------------
template <int C, bool OUTBF>
__global__ __launch_bounds__(256) void agg_k(const short* __restrict__ M,
                                             const int* __restrict__ src,
                                             const int* __restrict__ off,
                                             const float* __restrict__ bias,
                                             void* __restrict__ Hp, int N) {
    const int lane = threadIdx.x & 63;
    const int node = blockIdx.x * 4 + (threadIdx.x >> 6);
    if (node >= N) return;
    const int e0 = off[node], e1 = off[node + 1];

    if constexpr (C == 128) {
        const unsigned* __restrict__ M32 = (const unsigned*)M;   // 64 dwords/row
        float2 acc = make_float2(0.f, 0.f);
        for (int base = e0; base < e1; base += 64) {
            int e = base + lane;
            int s = (e < e1) ? src[e] : 0;
            int cnt = min(64, e1 - base);
            int i = 0;
            for (; i + 4 <= cnt; i += 4) {
                int s0 = __shfl(s, i),     s1 = __shfl(s, i + 1);
                int s2 = __shfl(s, i + 2), s3 = __shfl(s, i + 3);
                unsigned d0 = M32[(size_t)s0 * 64 + lane];
                unsigned d1 = M32[(size_t)s1 * 64 + lane];
                unsigned d2 = M32[(size_t)s2 * 64 + lane];
                unsigned d3 = M32[(size_t)s3 * 64 + lane];
                acc.x += (bflo(d0) + bflo(d1)) + (bflo(d2) + bflo(d3));
                acc.y += (bfhi(d0) + bfhi(d1)) + (bfhi(d2) + bfhi(d3));
            }
            for (; i < cnt; ++i) {
                int si = __shfl(s, i);
                unsigned d = M32[(size_t)si * 64 + lane];
                acc.x += bflo(d); acc.y += bfhi(d);
            }
        }
        float2 bv = *(const float2*)&bias[lane * 2];
        float hx = acc.x + bv.x, hy = acc.y + bv.y;
        if constexpr (OUTBF) {
            unsigned d = (unsigned)(unsigned short)f2bf(hx)
                       | ((unsigned)(unsigned short)f2bf(hy) << 16);
            ((unsigned*)Hp)[(size_t)node * 64 + lane] = d;
        } else {
            *(float2*)((float*)Hp + (size_t)node * 128 + lane * 2) = make_float2(hx, hy);
        }
    } else {
        const unsigned short* __restrict__ M16 = (const unsigned short*)M;
        float acc = 0.f;
        for (int base = e0; base < e1; base += 64) {
            int e = base + lane;
            int s = (e < e1) ? src[e] : 0;
            int cnt = min(64, e1 - base);
            int i = 0;
            for (; i + 4 <= cnt; i += 4) {
                int s0 = __shfl(s, i),     s1 = __shfl(s, i + 1);
                int s2 = __shfl(s, i + 2), s3 = __shfl(s, i + 3);
                float v0 = bflo((unsigned)M16[(size_t)s0 * 64 + lane]);
                float v1 = bflo((unsigned)M16[(size_t)s1 * 64 + lane]);
                float v2 = bflo((unsigned)M16[(size_t)s2 * 64 + lane]);
                float v3 = bflo((unsigned)M16[(size_t)s3 * 64 + lane]);
                acc += (v0 + v1) + (v2 + v3);
            }
            for (; i < cnt; ++i) {
                int si = __shfl(s, i);
                acc += bflo((unsigned)M16[(size_t)si * 64 + lane]);
            }
        }
        ((float*)Hp)[(size_t)node * 64 + lane] = acc + bias[lane];
    }
}

// ---------------------------------------------------------------------------
// BN column stats (sum, sumsq) over bf16 Hb. Lane covers a dword (2 ch);
// wave reads contiguous 256B rows. Per-block LDS reduce -> 256 atomics.
// ---------------------------------------------------------------------------
__global__ __launch_bounds__(256) void stats_k(const short* __restrict__ Hb,
                                               float* __restrict__ stats, int N) {
    const int lane = threadIdx.x & 63, wave = threadIdx.x >> 6;
    const unsigned* __restrict__ H32 = (const unsigned*)Hb;
    float2 sum = make_float2(0.f, 0.f), sq = make_float2(0.f, 0.f);
    for (int r = blockIdx.x * 4 + wave; r < N; r += gridDim.x * 4) {
        unsigned d = H32[(size_t)r * 64 + lane];
        float lo = bflo(d), hi = bfhi(d);
        sum.x += lo; sum.y += hi;
        sq.x = fmaf(lo, lo, sq.x); sq.y = fmaf(hi, hi, sq.y);
    }
    __shared__ float sL[4][256];
    sL[wave][lane * 2]           = sum.x;
    sL[wave][lane * 2 + 1]       = sum.y;
    sL[wave][128 + lane * 2]     = sq.x;
    sL[wave][128 + lane * 2 + 1] = sq.y;
    __syncthreads();
    int tid = threadIdx.x;   // [0,128) -> sums, [128,256) -> sumsqs
    float v = sL[0][tid] + sL[1][tid] + sL[2][tid] + sL[3][tid];
    atomicAdd(&stats[tid], v);
}

// stats -> per-channel scale/shift:  out = h*sc + sh
__global__ void bnfin_k(const float* __restrict__ stats, const float* __restrict__ gamma,
                        const float* __restrict__ beta, float* __restrict__ ss, float invN) {
    int c = threadIdx.x;   // 128 threads
    float mu  = stats[c] * invN;
    float var = fmaf(-mu, mu, stats[128 + c] * invN);
    float sc  = gamma[c] * rsqrtf(var + BN_EPS);
    ss[c]       = sc;
    ss[128 + c] = fmaf(-mu, sc, beta[c]);
}

// ---------------------------------------------------------------------------
extern "C" void kernel_launch(void* const* d_in, const int* in_sizes, int n_in,
                              void* d_out, int out_size, void* d_ws, size_t ws_size,
                              hipStream_t stream) {
    const float* x   = (const float*)d_in[0];
    const int*   src = (const int*)d_in[1];
    const int*   dst = (const int*)d_in[2];
    const float* W0  = (const float*)d_in[3];
    const float* b0  = (const float*)d_in[4];
    const float* W1  = (const float*)d_in[5];
    const float* b1  = (const float*)d_in[6];
    const float* W2  = (const float*)d_in[7];
    const float* b2  = (const float*)d_in[8];
    const float* g0  = (const float*)d_in[9];
    const float* be0 = (const float*)d_in[10];
    const float* g1  = (const float*)d_in[11];
    const float* be1 = (const float*)d_in[12];
    float* out = (float*)d_out;

    const int N = in_sizes[0] / 128;
    const int E = in_sizes[1];

    // workspace: bf16 M (N x 128) + bf16 Hb (N x 128) + bf16 X1 (N x 128) + misc
    char*  ws   = (char*)d_ws;
    size_t bufH = (size_t)N * 128 * sizeof(short);
    short* Mb = (short*)(ws);                 // conv GEMM output, bf16
    short* Hb = (short*)(ws + bufH);          // pre-BN agg output, bf16
    short* X1 = (short*)(ws + 2 * bufH);      // post-layer-1 activations, bf16
    size_t p  = 3 * bufH;
    p = (p + 255) & ~(size_t)255;
    int*   off = (int*)(ws + p);
    p += ((size_t)(N + 1) * sizeof(int) + 255) & ~(size_t)255;
    float* stats0 = (float*)(ws + p); p += 1024;
    float* stats1 = (float*)(ws + p); p += 1024;
    float* ss0    = (float*)(ws + p); p += 1024;
    float* ss1    = (float*)(ws + p); p += 1024;
    short* Wt0    = (short*)(ws + p); p += 128 * 128 * 2;
    short* Wt1    = (short*)(ws + p); p += 128 * 128 * 2;
    short* Wt2    = (short*)(ws + p); p += 128 * 64 * 2;

    const dim3 blk(256);
    const int gGemm  = (N + 127) / 128;
    const int gAgg   = (N + 3) / 4;            // one node per wave (proven best)
    const int gStats = 2048;
    const float invN = 1.f / (float)N;

    zero_k<<<2, blk, 0, stream>>>(stats0, 512);   // stats0+stats1 contiguous
    wtrans_k<<<64, blk, 0, stream>>>(W0, Wt0, 128, 128);
    wtrans_k<<<64, blk, 0, stream>>>(W1, Wt1, 128, 128);
    wtrans_k<<<32, blk, 0, stream>>>(W2, Wt2, 128, 64);
    build_off_k<<<(E + 256) / 256, blk, 0, stream>>>(dst, off, E, N);

    // ---- layer 0: M0 = bf16(x) @ W0 ; Hb = agg(M0)+b0 ; stats ----
    mgemm_k<128, 0><<<gGemm, blk, 0, stream>>>(x, Wt0, Mb, nullptr, nullptr, nullptr, N);
    agg_k<128, true><<<gAgg, blk, 0, stream>>>(Mb, src, off, b0, Hb, N);
    stats_k<<<gStats, blk, 0, stream>>>(Hb, stats0, N);
    bnfin_k<<<1, 128, 0, stream>>>(stats0, g0, be0, ss0, invN);

    // ---- layer 1: x1 = relu(BN(Hb)+x) fused into GEMM; M1 = x1 @ W1 ----
    mgemm_k<128, 1><<<gGemm, blk, 0, stream>>>(Hb, Wt1, Mb, ss0, x, X1, N);
    agg_k<128, true><<<gAgg, blk, 0, stream>>>(Mb, src, off, b1, Hb, N);
    stats_k<<<gStats, blk, 0, stream>>>(Hb, stats1, N);
    bnfin_k<<<1, 128, 0, stream>>>(stats1, g1, be1, ss1, invN);

    // ---- layer 2: x2 = relu(BN(Hb)+x1) fused; M2 = x2 @ W2 ; out = agg+b2 ----
    mgemm_k<64, 2><<<gGemm, blk, 0, stream>>>(Hb, Wt2, Mb, ss1, X1, nullptr, N);
    agg_k<64, false><<<gAgg, blk, 0, stream>>>(Mb, src, off, b2, out, N);
}

// Round 8
// 343.818 us; speedup vs baseline: 1.1062x; 1.0765x over previous
//
#include <hip/hip_runtime.h>

#define BN_EPS 1e-5f

typedef __attribute__((ext_vector_type(8))) short bf16x8;
typedef __attribute__((ext_vector_type(4))) float f32x4;

__device__ __forceinline__ short f2bf(float f) {
    union { float f; unsigned u; } v; v.f = f;
    unsigned r = (v.u + 0x7fffu + ((v.u >> 16) & 1u)) >> 16;
    return (short)r;
}
__device__ __forceinline__ float bflo(unsigned d) {
    union { unsigned u; float f; } v; v.u = d << 16; return v.f;
}
__device__ __forceinline__ float bfhi(unsigned d) {
    union { unsigned u; float f; } v; v.u = d & 0xffff0000u; return v.f;
}

// ---------------------------------------------------------------------------
// Fused prologue (single dispatch):
//   blocks [0, nbOff)          : CSR offsets from sorted dst
//   next 64 / 64 / 32 blocks   : W0/W1/W2 transpose+bf16
//   last block                 : zero stats0+stats1 (512 floats)
// ---------------------------------------------------------------------------
__global__ __launch_bounds__(256) void prologue_k(const int* __restrict__ dst,
                                                  int* __restrict__ off, int E, int N,
                                                  const float* __restrict__ W0, short* __restrict__ Wt0,
                                                  const float* __restrict__ W1, short* __restrict__ Wt1,
                                                  const float* __restrict__ W2, short* __restrict__ Wt2,
                                                  float* __restrict__ stats) {
    int b = blockIdx.x;
    const int nbOff = (E + 256) / 256;
    if (b < nbOff) {
        int i = b * 256 + threadIdx.x;
        if (i > E) return;
        int cur  = (i < E) ? dst[i] : N;
        int prev = (i == 0) ? -1 : dst[i - 1];
        for (int n = prev + 1; n <= cur; ++n) off[n] = i;
        return;
    }
    b -= nbOff;
    if (b < 64) {                       // W0: 128x128
        int i = b * 256 + threadIdx.x;
        int c = i / 128, k = i % 128;
        Wt0[i] = f2bf(W0[k * 128 + c]);
        return;
    }
    b -= 64;
    if (b < 64) {                       // W1: 128x128
        int i = b * 256 + threadIdx.x;
        int c = i / 128, k = i % 128;
        Wt1[i] = f2bf(W1[k * 128 + c]);
        return;
    }
    b -= 64;
    if (b < 32) {                       // W2: 128x64 -> Wt2[64][128]
        int i = b * 256 + threadIdx.x;
        int c = i / 128, k = i % 128;
        Wt2[i] = f2bf(W2[k * 64 + c]);
        return;
    }
    b -= 32;
    if (b == 0) {                       // zero stats0+stats1
        stats[threadIdx.x] = 0.f;
        stats[threadIdx.x + 256] = 0.f;
    }
}

// ---------------------------------------------------------------------------
// MFMA GEMM, 3 modes of A-input fusion (BN finalize folded into MODE 1/2):
//   MODE 0: A = bf16(X fp32)                                   (layer 0)
//   MODE 1: A = relu(Hb*sc+sh + R_fp32); also write A -> X1    (layer 1)
//   MODE 2: A = relu(Hb*sc+sh + R_bf16)                        (layer 2)
// sc/sh computed per-block in LDS from global stats (atomically accumulated).
// Hb is bf16 [N][128]. Output M row-major bf16 [N][OUTC].
// Block = 256 thr (4 waves), 128 rows. mfma_f32_16x16x32_bf16 (m89-verified).
// ---------------------------------------------------------------------------
template <int OUTC, int MODE>
__global__ __launch_bounds__(256) void mgemm_k(const void* __restrict__ Xp,
                                               const short* __restrict__ Wt,
                                               short* __restrict__ M,
                                               const float* __restrict__ stats,
                                               const float* __restrict__ gamma,
                                               const float* __restrict__ beta,
                                               float invN,
                                               const void* __restrict__ Rp,
                                               short* __restrict__ X1, int N) {
    constexpr int NR = OUTC / 16;
    __shared__ short sW[OUTC][136];          // 272B stride: 2-way conflict = free
    __shared__ float sSS[256];

    const int tid = threadIdx.x;
    if constexpr (MODE != 0) {
        if (tid < 128) {
            float mu  = stats[tid] * invN;
            float var = fmaf(-mu, mu, stats[128 + tid] * invN);
            float sc  = gamma[tid] * rsqrtf(var + BN_EPS);
            sSS[tid]       = sc;
            sSS[128 + tid] = fmaf(-mu, sc, beta[tid]);
        }
    }
    for (int q = tid; q < OUTC * 16; q += 256) {
        int r = q >> 4, s = q & 15;
        *(int4*)&sW[r][s * 8] = ((const int4*)Wt)[q];
    }
    __syncthreads();

    const int wave = tid >> 6, lane = tid & 63;
    const int lr = lane & 15, lg = lane >> 4;
    const int row0 = blockIdx.x * 128 + wave * 32;

    f32x4 acc[2][NR];
    #pragma unroll
    for (int m = 0; m < 2; ++m)
        #pragma unroll
        for (int n = 0; n < NR; ++n) acc[m][n] = (f32x4){0.f, 0.f, 0.f, 0.f};

    #pragma unroll
    for (int kk = 0; kk < 4; ++kk) {
        bf16x8 a[2];
        const int ch0 = kk * 32 + lg * 8;
        #pragma unroll
        for (int m = 0; m < 2; ++m) {
            int row = row0 + m * 16 + lr;
            float v[8] = {0.f, 0.f, 0.f, 0.f, 0.f, 0.f, 0.f, 0.f};
            if (row < N) {
                if constexpr (MODE == 0) {
                    const float4* p = (const float4*)((const float*)Xp + (size_t)row * 128 + ch0);
                    float4 h0 = p[0], h1 = p[1];
                    v[0] = h0.x; v[1] = h0.y; v[2] = h0.z; v[3] = h0.w;
                    v[4] = h1.x; v[5] = h1.y; v[6] = h1.z; v[7] = h1.w;
                } else {
                    int4 hb = *(const int4*)((const short*)Xp + (size_t)row * 128 + ch0);
                    v[0] = bflo(hb.x); v[1] = bfhi(hb.x);
                    v[2] = bflo(hb.y); v[3] = bfhi(hb.y);
                    v[4] = bflo(hb.z); v[5] = bfhi(hb.z);
                    v[6] = bflo(hb.w); v[7] = bfhi(hb.w);
                    float sc[8], sh[8];
                    #pragma unroll
                    for (int k = 0; k < 8; ++k) {
                        sc[k] = sSS[ch0 + k];
                        sh[k] = sSS[128 + ch0 + k];
                    }
                    float r[8];
                    if constexpr (MODE == 1) {
                        const float4* rp = (const float4*)((const float*)Rp + (size_t)row * 128 + ch0);
                        float4 r0 = rp[0], r1 = rp[1];
                        r[0] = r0.x; r[1] = r0.y; r[2] = r0.z; r[3] = r0.w;
                        r[4] = r1.x; r[5] = r1.y; r[6] = r1.z; r[7] = r1.w;
                    } else {
                        int4 rb = *(const int4*)((const short*)Rp + (size_t)row * 128 + ch0);
                        r[0] = bflo(rb.x); r[1] = bfhi(rb.x);
                        r[2] = bflo(rb.y); r[3] = bfhi(rb.y);
                        r[4] = bflo(rb.z); r[5] = bfhi(rb.z);
                        r[6] = bflo(rb.w); r[7] = bfhi(rb.w);
                    }
                    #pragma unroll
                    for (int k = 0; k < 8; ++k)
                        v[k] = fmaxf(fmaf(v[k], sc[k], sh[k]) + r[k], 0.f);
                }
            }
            #pragma unroll
            for (int k = 0; k < 8; ++k) a[m][k] = f2bf(v[k]);
            if constexpr (MODE == 1) {
                if (row < N) *(bf16x8*)&X1[(size_t)row * 128 + ch0] = a[m];
            }
        }
        #pragma unroll
        for (int n = 0; n < NR; ++n) {
            bf16x8 b = *(const bf16x8*)&sW[n * 16 + lr][kk * 32 + lg * 8];
            acc[0][n] = __builtin_amdgcn_mfma_f32_16x16x32_bf16(a[0], b, acc[0][n], 0, 0, 0);
            acc[1][n] = __builtin_amdgcn_mfma_f32_16x16x32_bf16(a[1], b, acc[1][n], 0, 0, 0);
        }
    }

    #pragma unroll
    for (int m = 0; m < 2; ++m)
        #pragma unroll
        for (int r = 0; r < 4; ++r) {
            int row = row0 + m * 16 + lg * 4 + r;
            if (row < N) {
                #pragma unroll
                for (int n = 0; n < NR; ++n)
                    M[(size_t)row * OUTC + n * 16 + lr] = f2bf(acc[m][n][r]);
            }
        }
}

// ---------------------------------------------------------------------------
// 128-ch segment-sum gather (dst sorted -> CSR). One node per wave; lane =
// dword (2 ch). 16 UNCONDITIONAL independent row-loads per batch (clamped
// uniform shfl index + 0/1 weight) -> 4KB in flight, no branches between
// loads. OUTBF: write bf16 (layers 0/1) else fp32.
// ---------------------------------------------------------------------------
template <bool OUTBF>
__global__ __launch_bounds__(256) void agg128_k(const short* __restrict__ M,
                                                const int* __restrict__ src,
                                                const int* __restrict__ off,
                                                const float* __restrict__ bias,
                                                void* __restrict__ Hp, int N) {
    const int lane = threadIdx.x & 63;
    const int node = blockIdx.x * 4 + (threadIdx.x >> 6);
    if (node >= N) return;
    const int e0 = off[node], e1 = off[node + 1];
    const unsigned* __restrict__ M32 = (const unsigned*)M;   // 64 dwords/row

    float accx = 0.f, accy = 0.f;
    for (int base = e0; base < e1; base += 64) {
        const int cnt = min(64, e1 - base);
        int e = base + lane;
        int s = (e < e1) ? src[e] : 0;
        for (int j = 0; j < cnt; j += 16) {
            unsigned d[16];
            float wt[16];
            #pragma unroll
            for (int i = 0; i < 16; ++i) {
                int idx = j + i;                       // wave-uniform
                int ii  = idx < cnt ? idx : cnt - 1;   // uniform clamp
                int si  = __shfl(s, ii);
                d[i]  = M32[(size_t)si * 64 + lane];
                wt[i] = idx < cnt ? 1.f : 0.f;
            }
            #pragma unroll
            for (int i = 0; i < 16; ++i) {
                accx = fmaf(wt[i], bflo(d[i]), accx);
                accy = fmaf(wt[i], bfhi(d[i]), accy);
            }
        }
    }
    float2 bv = *(const float2*)&bias[lane * 2];
    float hx = accx + bv.x, hy = accy + bv.y;
    if constexpr (OUTBF) {
        unsigned d = (unsigned)(unsigned short)f2bf(hx)
                   | ((unsigned)(unsigned short)f2bf(hy) << 16);
        ((unsigned*)Hp)[(size_t)node * 64 + lane] = d;
    } else {
        *(float2*)((float*)Hp + (size_t)node * 128 + lane * 2) = make_float2(hx, hy);
    }
}

// ---------------------------------------------------------------------------
// 64-ch segment-sum gather, fp32 out (final layer). One node per wave;
// 2 edges per load instruction: e2 = lane>>5, c = lane&31 (dword = 2 ch).
// 8 loads per 16-edge batch, per-lane clamped bpermute index + weight.
// Butterfly over bit 5 combines the two edge halves.
// ---------------------------------------------------------------------------
__global__ __launch_bounds__(256) void agg64_k(const short* __restrict__ M,
                                               const int* __restrict__ src,
                                               const int* __restrict__ off,
                                               const float* __restrict__ bias,
                                               float* __restrict__ out, int N) {
    const int lane = threadIdx.x & 63;
    const int node = blockIdx.x * 4 + (threadIdx.x >> 6);
    if (node >= N) return;
    const int e0 = off[node], e1 = off[node + 1];
    const unsigned* __restrict__ M32 = (const unsigned*)M;   // 32 dwords/row
    const int e2 = lane >> 5, c = lane & 31;

    float accx = 0.f, accy = 0.f;
    for (int base = e0; base < e1; base += 64) {
        const int cnt = min(64, e1 - base);
        int e = base + lane;
        int s = (e < e1) ? src[e] : 0;
        for (int j = 0; j < cnt; j += 16) {
            unsigned d[8];
            float wt[8];
            #pragma unroll
            for (int i = 0; i < 8; ++i) {
                int idx = j + i * 2 + e2;              // per-lane (e2)
                int ii  = idx < cnt ? idx : cnt - 1;
                int si  = __shfl(s, ii);
                d[i]  = M32[(size_t)si * 32 + c];
                wt[i] = idx < cnt ? 1.f : 0.f;
            }
            #pragma unroll
            for (int i = 0; i < 8; ++i) {
                accx = fmaf(wt[i], bflo(d[i]), accx);
                accy = fmaf(wt[i], bfhi(d[i]), accy);
            }
        }
    }
    accx += __shfl_xor(accx, 32);
    accy += __shfl_xor(accy, 32);
    if (e2 == 0) {
        float2 bv = *(const float2*)&bias[c * 2];
        *(float2*)&out[(size_t)node * 64 + c * 2] = make_float2(accx + bv.x, accy + bv.y);
    }
}

// ---------------------------------------------------------------------------
// BN column stats (sum, sumsq) over bf16 Hb. Lane = dword (2 ch); wave reads
// contiguous 256B rows. Per-block LDS reduce -> 256 atomics.
// ---------------------------------------------------------------------------
__global__ __launch_bounds__(256) void stats_k(const short* __restrict__ Hb,
                                               float* __restrict__ stats, int N) {
    const int lane = threadIdx.x & 63, wave = threadIdx.x >> 6;
    const unsigned* __restrict__ H32 = (const unsigned*)Hb;
    float2 sum = make_float2(0.f, 0.f), sq = make_float2(0.f, 0.f);
    for (int r = blockIdx.x * 4 + wave; r < N; r += gridDim.x * 4) {
        unsigned d = H32[(size_t)r * 64 + lane];
        float lo = bflo(d), hi = bfhi(d);
        sum.x += lo; sum.y += hi;
        sq.x = fmaf(lo, lo, sq.x); sq.y = fmaf(hi, hi, sq.y);
    }
    __shared__ float sL[4][256];
    sL[wave][lane * 2]           = sum.x;
    sL[wave][lane * 2 + 1]       = sum.y;
    sL[wave][128 + lane * 2]     = sq.x;
    sL[wave][128 + lane * 2 + 1] = sq.y;
    __syncthreads();
    int tid = threadIdx.x;   // [0,128) -> sums, [128,256) -> sumsqs
    float v = sL[0][tid] + sL[1][tid] + sL[2][tid] + sL[3][tid];
    atomicAdd(&stats[tid], v);
}

// ---------------------------------------------------------------------------
extern "C" void kernel_launch(void* const* d_in, const int* in_sizes, int n_in,
                              void* d_out, int out_size, void* d_ws, size_t ws_size,
                              hipStream_t stream) {
    const float* x   = (const float*)d_in[0];
    const int*   src = (const int*)d_in[1];
    const int*   dst = (const int*)d_in[2];
    const float* W0  = (const float*)d_in[3];
    const float* b0  = (const float*)d_in[4];
    const float* W1  = (const float*)d_in[5];
    const float* b1  = (const float*)d_in[6];
    const float* W2  = (const float*)d_in[7];
    const float* b2  = (const float*)d_in[8];
    const float* g0  = (const float*)d_in[9];
    const float* be0 = (const float*)d_in[10];
    const float* g1  = (const float*)d_in[11];
    const float* be1 = (const float*)d_in[12];
    float* out = (float*)d_out;

    const int N = in_sizes[0] / 128;
    const int E = in_sizes[1];

    // workspace: bf16 M (N x 128) + bf16 Hb (N x 128) + bf16 X1 (N x 128) + misc
    char*  ws   = (char*)d_ws;
    size_t bufH = (size_t)N * 128 * sizeof(short);
    short* Mb = (short*)(ws);                 // conv GEMM output, bf16
    short* Hb = (short*)(ws + bufH);          // pre-BN agg output, bf16
    short* X1 = (short*)(ws + 2 * bufH);      // post-layer-1 activations, bf16
    size_t p  = 3 * bufH;
    p = (p + 255) & ~(size_t)255;
    int*   off = (int*)(ws + p);
    p += ((size_t)(N + 1) * sizeof(int) + 255) & ~(size_t)255;
    float* stats0 = (float*)(ws + p); p += 1024;   // contiguous with stats1
    float* stats1 = (float*)(ws + p); p += 1024;
    short* Wt0    = (short*)(ws + p); p += 128 * 128 * 2;
    short* Wt1    = (short*)(ws + p); p += 128 * 128 * 2;
    short* Wt2    = (short*)(ws + p); p += 128 * 64 * 2;

    const dim3 blk(256);
    const int nbOff  = (E + 256) / 256;
    const int gPro   = nbOff + 64 + 64 + 32 + 1;
    const int gGemm  = (N + 127) / 128;
    const int gAgg   = (N + 3) / 4;            // one node per wave
    const int gStats = 2048;
    const float invN = 1.f / (float)N;

    prologue_k<<<gPro, blk, 0, stream>>>(dst, off, E, N, W0, Wt0, W1, Wt1, W2, Wt2, stats0);

    // ---- layer 0 ----
    mgemm_k<128, 0><<<gGemm, blk, 0, stream>>>(x, Wt0, Mb, nullptr, nullptr, nullptr, 0.f,
                                               nullptr, nullptr, N);
    agg128_k<true><<<gAgg, blk, 0, stream>>>(Mb, src, off, b0, Hb, N);
    stats_k<<<gStats, blk, 0, stream>>>(Hb, stats0, N);

    // ---- layer 1 (BN finalize folded into GEMM prologue) ----
    mgemm_k<128, 1><<<gGemm, blk, 0, stream>>>(Hb, Wt1, Mb, stats0, g0, be0, invN, x, X1, N);
    agg128_k<true><<<gAgg, blk, 0, stream>>>(Mb, src, off, b1, Hb, N);
    stats_k<<<gStats, blk, 0, stream>>>(Hb, stats1, N);

    // ---- layer 2 ----
    mgemm_k<64, 2><<<gGemm, blk, 0, stream>>>(Hb, Wt2, Mb, stats1, g1, be1, invN, X1, nullptr, N);
    agg64_k<<<gAgg, blk, 0, stream>>>(Mb, src, off, b2, out, N);
}